// Round 1
// baseline (391.006 us; speedup 1.0000x reference)
//
#include <hip/hip_runtime.h>
#include <math.h>

#define N_NODES 16384
#define IN_DIM  512
#define HID_DIM 256
#define OUT_DIM 128
#define MAXDEG  128

// ---------------------------------------------------------------------------
// Kernel 1: scan dense adjacency (1.07 GB), build fixed-width adjacency lists,
// degree counts, and din = deg^{-1/2}. One 64-lane wave per row, float4 loads.
// Deterministic ballot/popcount packing.
// ---------------------------------------------------------------------------
__global__ __launch_bounds__(256) void build_adj_kernel(
    const float* __restrict__ A,
    int* __restrict__ adj,
    int* __restrict__ cnt,
    float* __restrict__ din) {
    const int lane = threadIdx.x & 63;
    const int row  = blockIdx.x * 4 + (threadIdx.x >> 6);
    const float4* arow = (const float4*)(A + (size_t)row * N_NODES);
    const unsigned long long lt = (1ull << lane) - 1ull;
    int base = 0;
    for (int chunk = 0; chunk < N_NODES / 256; ++chunk) {
        float4 v = arow[chunk * 64 + lane];
        bool nz[4] = {v.x != 0.f, v.y != 0.f, v.z != 0.f, v.w != 0.f};
        const int c0 = chunk * 256 + lane * 4;
        #pragma unroll
        for (int i = 0; i < 4; ++i) {
            unsigned long long m = __ballot(nz[i]);
            if (nz[i]) {
                int p = base + __popcll(m & lt);
                if (p < MAXDEG) adj[row * MAXDEG + p] = c0 + i;
            }
            base += __popcll(m);
        }
    }
    if (lane == 0) {
        cnt[row] = base < MAXDEG ? base : MAXDEG;
        din[row] = base > 0 ? 1.0f / sqrtf((float)base) : 0.0f;
    }
}

// ---------------------------------------------------------------------------
// Kernel 2: C[m][n] = din[m] * sum_k A[m][k] * B[k][n]
// 64x64 tile, 256 threads, 4x4 micro-tile per thread, K-chunk 16.
// M=16384 (mult of 64), N in {256,128}, K in {512,256} (mult of 16).
// ---------------------------------------------------------------------------
__global__ __launch_bounds__(256) void gemm_scale_kernel(
    const float* __restrict__ A, const float* __restrict__ B,
    const float* __restrict__ din, float* __restrict__ C,
    int K, int N) {
    __shared__ float xs[64][17];   // +1 pad: kill 4-way bank conflict
    __shared__ float ws[16][64];
    const int t  = threadIdx.x;
    const int tx = t & 15, ty = t >> 4;
    const int m0 = blockIdx.y * 64, n0 = blockIdx.x * 64;
    float acc[4][4] = {};
    for (int kt = 0; kt < K; kt += 16) {
        {
            const int r = t >> 2, c4 = (t & 3) * 4;
            const float4 v = *(const float4*)(A + (size_t)(m0 + r) * K + kt + c4);
            xs[r][c4 + 0] = v.x; xs[r][c4 + 1] = v.y;
            xs[r][c4 + 2] = v.z; xs[r][c4 + 3] = v.w;
        }
        {
            const int r = t >> 4, c4 = (t & 15) * 4;
            *(float4*)&ws[r][c4] = *(const float4*)(B + (size_t)(kt + r) * N + n0 + c4);
        }
        __syncthreads();
        #pragma unroll
        for (int k = 0; k < 16; ++k) {
            float a[4], b[4];
            #pragma unroll
            for (int i = 0; i < 4; ++i) a[i] = xs[ty * 4 + i][k];
            #pragma unroll
            for (int j = 0; j < 4; ++j) b[j] = ws[k][tx * 4 + j];
            #pragma unroll
            for (int i = 0; i < 4; ++i)
                #pragma unroll
                for (int j = 0; j < 4; ++j)
                    acc[i][j] += a[i] * b[j];
        }
        __syncthreads();
    }
    #pragma unroll
    for (int i = 0; i < 4; ++i) {
        const int row = m0 + ty * 4 + i;
        const float s = din[row];
        #pragma unroll
        for (int j = 0; j < 4; ++j)
            C[(size_t)row * N + n0 + tx * 4 + j] = acc[i][j] * s;
    }
}

// ---------------------------------------------------------------------------
// Kernel 3: per-node sparse aggregation + bias (+ELU) + row L2-normalize.
// Block per node, thread per column. Neighbor h-rows are coalesced gathers
// that hit L2/LLC (h1 = 16.8 MB).
// ---------------------------------------------------------------------------
template<int D, bool DO_ELU>
__global__ void agg_kernel(const float* __restrict__ h,
                           const int* __restrict__ adj,
                           const int* __restrict__ cnt,
                           const float* __restrict__ din,
                           const float* __restrict__ bias,
                           float* __restrict__ out) {
    __shared__ int   s_adj[MAXDEG];
    __shared__ float s_red[D / 64];
    const int node = blockIdx.x;
    const int col  = threadIdx.x;
    const int n    = cnt[node];
    for (int e = col; e < n; e += D) s_adj[e] = adj[node * MAXDEG + e];
    __syncthreads();
    float acc = 0.f;
    for (int e = 0; e < n; ++e) acc += h[(size_t)s_adj[e] * D + col];
    float val = acc * din[node] + bias[col];
    if (DO_ELU) val = val > 0.f ? val : expm1f(val);
    // row L2 norm across the block
    float ss = val * val;
    #pragma unroll
    for (int off = 32; off > 0; off >>= 1) ss += __shfl_xor(ss, off, 64);
    if ((col & 63) == 0) s_red[col >> 6] = ss;
    __syncthreads();
    float tot = 0.f;
    #pragma unroll
    for (int w = 0; w < D / 64; ++w) tot += s_red[w];
    const float nrm = sqrtf(tot);
    out[(size_t)node * D + col] = val / fmaxf(nrm, 1e-12f);
}

// ---------------------------------------------------------------------------
extern "C" void kernel_launch(void* const* d_in, const int* in_sizes, int n_in,
                              void* d_out, int out_size, void* d_ws, size_t ws_size,
                              hipStream_t stream) {
    const float* x  = (const float*)d_in[0];
    const float* A  = (const float*)d_in[1];
    const float* W1 = (const float*)d_in[2];
    const float* b1 = (const float*)d_in[3];
    const float* W2 = (const float*)d_in[4];
    const float* b2 = (const float*)d_in[5];

    float* out = (float*)d_out;
    float* z2  = out;                                   // 16384 x 128 (first in tuple)
    float* z1  = out + (size_t)N_NODES * OUT_DIM;       // 16384 x 256

    char* p = (char*)d_ws;
    int*   adj = (int*)p;   p += (size_t)N_NODES * MAXDEG * sizeof(int);   // 8.39 MB
    int*   cnt = (int*)p;   p += (size_t)N_NODES * sizeof(int);
    float* din = (float*)p; p += (size_t)N_NODES * sizeof(float);
    float* h1  = (float*)p; p += (size_t)N_NODES * HID_DIM * sizeof(float); // 16.8 MB
    float* h2  = (float*)p;                                                 // 8.39 MB

    // 1) adjacency structure + degrees (reads the 1.07 GB matrix once)
    build_adj_kernel<<<N_NODES / 4, 256, 0, stream>>>(A, adj, cnt, din);

    // 2) h1 = (x @ W1) * din[:,None]
    gemm_scale_kernel<<<dim3(HID_DIM / 64, N_NODES / 64), 256, 0, stream>>>(
        x, W1, din, h1, IN_DIM, HID_DIM);

    // 3) z1 = l2norm(elu(agg(h1) * din + b1))
    agg_kernel<HID_DIM, true><<<N_NODES, HID_DIM, 0, stream>>>(
        h1, adj, cnt, din, b1, z1);

    // 4) h2 = (z1 @ W2) * din[:,None]
    gemm_scale_kernel<<<dim3(OUT_DIM / 64, N_NODES / 64), 256, 0, stream>>>(
        z1, W2, din, h2, HID_DIM, OUT_DIM);

    // 5) z2 = l2norm(agg(h2) * din + b2)
    agg_kernel<OUT_DIM, false><<<N_NODES, OUT_DIM, 0, stream>>>(
        h2, adj, cnt, din, b2, z2);
}

// Round 2
// 343.329 us; speedup vs baseline: 1.1389x; 1.1389x over previous
//
#include <hip/hip_runtime.h>
#include <math.h>

#define N_NODES 16384
#define IN_DIM  512
#define HID_DIM 256
#define OUT_DIM 128
#define MAXDEG  128

// ---------------------------------------------------------------------------
// 64x64 f32 GEMM tile: C[m][n] = sum_k A[m][k]*B[k][n]  (no scaling).
// 256 threads, 4x4 micro-tile, K-chunk 16. As stored transposed [k][m] so
// both fragments are ds_read_b128. As pad 68 -> write conflicts are 2-way
// (free); Bs reads are 16 distinct 16B lines covering all banks.
// ---------------------------------------------------------------------------
__device__ __forceinline__ void gemm_tile(
    const float* __restrict__ Amat, const float* __restrict__ B,
    float* __restrict__ C, int K, int N, int m0, int n0,
    float (*As)[68], float (*Bs)[64]) {
    const int t  = threadIdx.x;
    const int tx = t & 15, ty = t >> 4;
    float acc[4][4] = {};
    for (int kt = 0; kt < K; kt += 16) {
        {   // load + transpose A tile: thread t -> row m=t>>2, k4=(t&3)*4
            const int m = t >> 2, k4 = (t & 3) * 4;
            const float4 v = *(const float4*)(Amat + (size_t)(m0 + m) * K + kt + k4);
            As[k4 + 0][m] = v.x; As[k4 + 1][m] = v.y;
            As[k4 + 2][m] = v.z; As[k4 + 3][m] = v.w;
        }
        {   // load B tile [k][n]
            const int k = t >> 4, c4 = (t & 15) * 4;
            *(float4*)&Bs[k][c4] = *(const float4*)(B + (size_t)(kt + k) * N + n0 + c4);
        }
        __syncthreads();
        #pragma unroll
        for (int k = 0; k < 16; ++k) {
            const float4 a = *(const float4*)&As[k][ty * 4];
            const float4 b = *(const float4*)&Bs[k][tx * 4];
            const float av[4] = {a.x, a.y, a.z, a.w};
            const float bv[4] = {b.x, b.y, b.z, b.w};
            #pragma unroll
            for (int i = 0; i < 4; ++i)
                #pragma unroll
                for (int j = 0; j < 4; ++j)
                    acc[i][j] += av[i] * bv[j];
        }
        __syncthreads();
    }
    #pragma unroll
    for (int i = 0; i < 4; ++i)
        *(float4*)(C + (size_t)(m0 + ty * 4 + i) * N + n0 + tx * 4) =
            make_float4(acc[i][0], acc[i][1], acc[i][2], acc[i][3]);
}

// ---------------------------------------------------------------------------
// Fused kernel: every 5th block computes one 64x64 tile of h1 = x @ W1
// (1024 tiles); the other 4096 blocks scan the 1.07 GB adjacency matrix
// (4 rows/block, wave per row) building adj lists + deg^-1/2. The
// compute-bound GEMM hides under the HBM-bound scan.
// ---------------------------------------------------------------------------
__global__ __launch_bounds__(256) void scan_gemm_kernel(
    const float* __restrict__ A,
    int* __restrict__ adj, int* __restrict__ cnt, float* __restrict__ din,
    const float* __restrict__ X, const float* __restrict__ W1,
    float* __restrict__ H1) {
    __shared__ float As[16][68];
    __shared__ float Bs[16][64];
    const int bid = blockIdx.x;
    if (bid % 5 == 0) {
        const int g  = bid / 5;            // 0..1023
        const int n0 = (g & 3) * 64;       // HID_DIM/64 = 4
        const int m0 = (g >> 2) * 64;      // 256 row tiles
        gemm_tile(X, W1, H1, IN_DIM, HID_DIM, m0, n0, As, Bs);
        return;
    }
    const int s    = bid - bid / 5 - 1;    // 0..4095
    const int lane = threadIdx.x & 63;
    const int row  = s * 4 + (threadIdx.x >> 6);
    const float4* arow = (const float4*)(A + (size_t)row * N_NODES);
    const unsigned long long lt = (1ull << lane) - 1ull;
    int base = 0;
    for (int chunk = 0; chunk < N_NODES / 256; ++chunk) {
        const float4 v = arow[chunk * 64 + lane];
        const bool nz[4] = {v.x != 0.f, v.y != 0.f, v.z != 0.f, v.w != 0.f};
        const int c0 = chunk * 256 + lane * 4;
        #pragma unroll
        for (int i = 0; i < 4; ++i) {
            const unsigned long long m = __ballot(nz[i]);
            if (nz[i]) {
                const int p = base + __popcll(m & lt);
                if (p < MAXDEG) adj[row * MAXDEG + p] = c0 + i;
            }
            base += __popcll(m);
        }
    }
    if (lane == 0) {
        cnt[row] = base < MAXDEG ? base : MAXDEG;
        din[row] = base > 0 ? 1.0f / sqrtf((float)base) : 0.0f;
    }
}

// ---------------------------------------------------------------------------
// Standalone GEMM (h2 = z1 @ W2, unscaled).
// ---------------------------------------------------------------------------
__global__ __launch_bounds__(256) void gemm_kernel(
    const float* __restrict__ Amat, const float* __restrict__ B,
    float* __restrict__ C, int K, int N) {
    __shared__ float As[16][68];
    __shared__ float Bs[16][64];
    gemm_tile(Amat, B, C, K, N, blockIdx.y * 64, blockIdx.x * 64, As, Bs);
}

// ---------------------------------------------------------------------------
// Aggregation: one wave per node, VPT cols/lane (vector gathers).
// out = l2norm( [elu]( sum_e h[adj[e]]*din[adj[e]] * din[node] + b ) )
// ---------------------------------------------------------------------------
template<int D, int VPT, bool DO_ELU>
__global__ __launch_bounds__(64) void agg_kernel(
    const float* __restrict__ h, const int* __restrict__ adj,
    const int* __restrict__ cnt, const float* __restrict__ din,
    const float* __restrict__ bias, float* __restrict__ out) {
    __shared__ int   s_adj[MAXDEG];
    __shared__ float s_dsc[MAXDEG];
    const int node = blockIdx.x;
    const int lane = threadIdx.x;
    const int n    = cnt[node];
    for (int e = lane; e < n; e += 64) {
        const int s = adj[node * MAXDEG + e];
        s_adj[e] = s;
        s_dsc[e] = din[s];
    }
    __syncthreads();
    const int c0 = lane * VPT;
    float acc[VPT] = {};
    int e = 0;
    for (; e + 4 <= n; e += 4) {
        #pragma unroll
        for (int u = 0; u < 4; ++u) {
            const float* hp = h + (size_t)s_adj[e + u] * D + c0;
            const float w  = s_dsc[e + u];
            if (VPT == 4) {
                const float4 v = *(const float4*)hp;
                acc[0] += v.x * w; acc[1] += v.y * w;
                acc[2] += v.z * w; acc[3 % VPT] += v.w * w;
            } else {
                const float2 v = *(const float2*)hp;
                acc[0] += v.x * w; acc[1 % VPT] += v.y * w;
            }
        }
    }
    for (; e < n; ++e) {
        const float* hp = h + (size_t)s_adj[e] * D + c0;
        const float w  = s_dsc[e];
        if (VPT == 4) {
            const float4 v = *(const float4*)hp;
            acc[0] += v.x * w; acc[1] += v.y * w;
            acc[2] += v.z * w; acc[3 % VPT] += v.w * w;
        } else {
            const float2 v = *(const float2*)hp;
            acc[0] += v.x * w; acc[1 % VPT] += v.y * w;
        }
    }
    const float dn = din[node];
    float val[VPT];
    float ss = 0.f;
    #pragma unroll
    for (int u = 0; u < VPT; ++u) {
        float v = acc[u] * dn + bias[c0 + u];
        if (DO_ELU) v = v > 0.f ? v : expm1f(v);
        val[u] = v;
        ss += v * v;
    }
    #pragma unroll
    for (int off = 32; off > 0; off >>= 1) ss += __shfl_xor(ss, off, 64);
    const float inv = 1.0f / fmaxf(sqrtf(ss), 1e-12f);
    #pragma unroll
    for (int u = 0; u < VPT; ++u) val[u] *= inv;
    if (VPT == 4)
        *(float4*)(out + (size_t)node * D + c0) =
            make_float4(val[0], val[1], val[2], val[3 % VPT]);
    else
        *(float2*)(out + (size_t)node * D + c0) = make_float2(val[0], val[1 % VPT]);
}

// ---------------------------------------------------------------------------
extern "C" void kernel_launch(void* const* d_in, const int* in_sizes, int n_in,
                              void* d_out, int out_size, void* d_ws, size_t ws_size,
                              hipStream_t stream) {
    const float* x  = (const float*)d_in[0];
    const float* A  = (const float*)d_in[1];
    const float* W1 = (const float*)d_in[2];
    const float* b1 = (const float*)d_in[3];
    const float* W2 = (const float*)d_in[4];
    const float* b2 = (const float*)d_in[5];

    float* out = (float*)d_out;
    float* z2  = out;                                   // 16384 x 128
    float* z1  = out + (size_t)N_NODES * OUT_DIM;       // 16384 x 256

    char* p = (char*)d_ws;
    int*   adj = (int*)p;   p += (size_t)N_NODES * MAXDEG * sizeof(int);
    int*   cnt = (int*)p;   p += (size_t)N_NODES * sizeof(int);
    float* din = (float*)p; p += (size_t)N_NODES * sizeof(float);
    float* h1  = (float*)p; p += (size_t)N_NODES * HID_DIM * sizeof(float);
    float* h2  = (float*)p;

    // 1) [A-scan || h1 = x @ W1] fused (GEMM hides under the 1.07 GB read)
    scan_gemm_kernel<<<5120, 256, 0, stream>>>(A, adj, cnt, din, x, W1, h1);

    // 2) z1 = l2norm(elu(agg(h1*din) * din + b1))
    agg_kernel<HID_DIM, 4, true><<<N_NODES, 64, 0, stream>>>(
        h1, adj, cnt, din, b1, z1);

    // 3) h2 = z1 @ W2
    gemm_kernel<<<dim3(OUT_DIM / 64, N_NODES / 64), 256, 0, stream>>>(
        z1, W2, h2, HID_DIM, OUT_DIM);

    // 4) z2 = l2norm(agg(h2*din) * din + b2)
    agg_kernel<OUT_DIM, 2, false><<<N_NODES, 64, 0, stream>>>(
        h2, adj, cnt, din, b2, z2);
}

// Round 3
// 262.062 us; speedup vs baseline: 1.4920x; 1.3101x over previous
//
#include <hip/hip_runtime.h>
#include <math.h>

#define N_NODES 16384
#define IN_DIM  512
#define HID_DIM 256
#define OUT_DIM 128
#define MAXDEG  128

typedef float f4v __attribute__((ext_vector_type(4)));

__device__ __forceinline__ float bf2f(unsigned short u) {
    return __uint_as_float(((unsigned int)u) << 16);
}
__device__ __forceinline__ unsigned short f2bf(float f) {
    unsigned int u = __float_as_uint(f);
    return (unsigned short)((u + 0x7FFFu + ((u >> 16) & 1u)) >> 16);
}

// ---------------------------------------------------------------------------
// 64x64 f32 GEMM tile: C[m][n] = sum_k A[m][k]*B[k][n]. 256 threads, 4x4
// micro-tile, K-chunk 16, As transposed [k][m] so fragments are ds_read_b128.
// OutT = float (f32 store) or ushort (bf16 RNE store).
// ---------------------------------------------------------------------------
template<typename OutT>
__device__ __forceinline__ void gemm_tile(
    const float* __restrict__ Amat, const float* __restrict__ B,
    OutT* __restrict__ C, int K, int N, int m0, int n0,
    float (*As)[68], float (*Bs)[64]) {
    const int t  = threadIdx.x;
    const int tx = t & 15, ty = t >> 4;
    float acc[4][4] = {};
    for (int kt = 0; kt < K; kt += 16) {
        {
            const int m = t >> 2, k4 = (t & 3) * 4;
            const float4 v = *(const float4*)(Amat + (size_t)(m0 + m) * K + kt + k4);
            As[k4 + 0][m] = v.x; As[k4 + 1][m] = v.y;
            As[k4 + 2][m] = v.z; As[k4 + 3][m] = v.w;
        }
        {
            const int k = t >> 4, c4 = (t & 15) * 4;
            *(float4*)&Bs[k][c4] = *(const float4*)(B + (size_t)(kt + k) * N + n0 + c4);
        }
        __syncthreads();
        #pragma unroll
        for (int k = 0; k < 16; ++k) {
            const float4 a = *(const float4*)&As[k][ty * 4];
            const float4 b = *(const float4*)&Bs[k][tx * 4];
            const float av[4] = {a.x, a.y, a.z, a.w};
            const float bv[4] = {b.x, b.y, b.z, b.w};
            #pragma unroll
            for (int i = 0; i < 4; ++i)
                #pragma unroll
                for (int j = 0; j < 4; ++j)
                    acc[i][j] += av[i] * bv[j];
        }
        __syncthreads();
    }
    #pragma unroll
    for (int i = 0; i < 4; ++i) {
        const size_t off = (size_t)(m0 + ty * 4 + i) * N + n0 + tx * 4;
        if constexpr (sizeof(OutT) == 2) {
            ushort4 o;
            o.x = f2bf(acc[i][0]); o.y = f2bf(acc[i][1]);
            o.z = f2bf(acc[i][2]); o.w = f2bf(acc[i][3]);
            *(ushort4*)(C + off) = o;
        } else {
            *(float4*)(C + off) =
                make_float4(acc[i][0], acc[i][1], acc[i][2], acc[i][3]);
        }
    }
}

// ---------------------------------------------------------------------------
// Fused: every 5th block = one 64x64 tile of h1 = x @ W1 (bf16 out, 1024
// tiles); other 4096 blocks scan the 1.07 GB adjacency (4 rows/block, wave
// per row; nontemporal streaming loads, 2-chunk unroll) building adj + din.
// ---------------------------------------------------------------------------
__global__ __launch_bounds__(256) void scan_gemm_kernel(
    const float* __restrict__ A,
    int* __restrict__ adj, int* __restrict__ cnt, float* __restrict__ din,
    const float* __restrict__ X, const float* __restrict__ W1,
    unsigned short* __restrict__ H1) {
    __shared__ float As[16][68];
    __shared__ float Bs[16][64];
    const int bid = blockIdx.x;
    if (bid % 5 == 0) {
        const int g  = bid / 5;
        const int n0 = (g & 3) * 64;
        const int m0 = (g >> 2) * 64;
        gemm_tile<unsigned short>(X, W1, H1, IN_DIM, HID_DIM, m0, n0, As, Bs);
        return;
    }
    const int s    = bid - bid / 5 - 1;
    const int lane = threadIdx.x & 63;
    const int row  = s * 4 + (threadIdx.x >> 6);
    const f4v* arow = (const f4v*)(A + (size_t)row * N_NODES);
    const unsigned long long lt = (1ull << lane) - 1ull;
    int base = 0;
    for (int chunk = 0; chunk < N_NODES / 256; chunk += 2) {
        const f4v v0 = __builtin_nontemporal_load(&arow[chunk * 64 + lane]);
        const f4v v1 = __builtin_nontemporal_load(&arow[chunk * 64 + 64 + lane]);
        const float vv[8] = {v0.x, v0.y, v0.z, v0.w, v1.x, v1.y, v1.z, v1.w};
        #pragma unroll
        for (int h = 0; h < 2; ++h) {
            const int c0 = (chunk + h) * 256 + lane * 4;
            #pragma unroll
            for (int i = 0; i < 4; ++i) {
                const bool nz = vv[h * 4 + i] != 0.f;
                const unsigned long long m = __ballot(nz);
                if (nz) {
                    const int p = base + __popcll(m & lt);
                    if (p < MAXDEG) adj[row * MAXDEG + p] = c0 + i;
                }
                base += __popcll(m);
            }
        }
    }
    if (lane == 0) {
        cnt[row] = base < MAXDEG ? base : MAXDEG;
        din[row] = base > 0 ? 1.0f / sqrtf((float)base) : 0.0f;
    }
}

// ---------------------------------------------------------------------------
// Standalone GEMM (h2 = z1 @ W2 -> bf16).
// ---------------------------------------------------------------------------
__global__ __launch_bounds__(256) void gemm_kernel(
    const float* __restrict__ Amat, const float* __restrict__ B,
    unsigned short* __restrict__ C, int K, int N) {
    __shared__ float As[16][68];
    __shared__ float Bs[16][64];
    gemm_tile<unsigned short>(Amat, B, C, K, N, blockIdx.y * 64, blockIdx.x * 64,
                              As, Bs);
}

// ---------------------------------------------------------------------------
// Aggregation: 4 nodes per 256-thread block (one wave per node), bf16 row
// gathers, unroll-8 edge loop, f32 accumulate + ELU + row L2-norm, f32 out.
// out[v] = l2norm( [elu]( din[v] * sum_e h[adj_e]*din[adj_e] + b ) )
// ---------------------------------------------------------------------------
template<int D, int VPT, bool DO_ELU>
__global__ __launch_bounds__(256) void agg_kernel(
    const unsigned short* __restrict__ h, const int* __restrict__ adj,
    const int* __restrict__ cnt, const float* __restrict__ din,
    const float* __restrict__ bias, float* __restrict__ out) {
    __shared__ int   s_adj[4][MAXDEG];
    __shared__ float s_dsc[4][MAXDEG];
    const int wid  = threadIdx.x >> 6;
    const int lane = threadIdx.x & 63;
    const int node = blockIdx.x * 4 + wid;
    const int n    = cnt[node];
    for (int e = lane; e < n; e += 64) {
        const int s = adj[node * MAXDEG + e];
        s_adj[wid][e] = s;
        s_dsc[wid][e] = din[s];
    }
    __syncthreads();
    const int c0 = lane * VPT;
    float acc[VPT] = {};
    #define GATHER(idx)                                                        \
        do {                                                                   \
            const unsigned short* hp =                                         \
                h + (size_t)s_adj[wid][idx] * D + c0;                          \
            const float w = s_dsc[wid][idx];                                   \
            if (VPT == 4) {                                                    \
                const ushort4 u = *(const ushort4*)hp;                         \
                acc[0] += bf2f(u.x) * w; acc[1] += bf2f(u.y) * w;              \
                acc[2] += bf2f(u.z) * w; acc[3 % VPT] += bf2f(u.w) * w;        \
            } else {                                                           \
                const ushort2 u = *(const ushort2*)hp;                         \
                acc[0] += bf2f(u.x) * w; acc[1 % VPT] += bf2f(u.y) * w;        \
            }                                                                  \
        } while (0)
    int e = 0;
    for (; e + 8 <= n; e += 8) {
        #pragma unroll
        for (int u = 0; u < 8; ++u) GATHER(e + u);
    }
    for (; e < n; ++e) GATHER(e);
    #undef GATHER
    const float dn = din[node];
    float val[VPT];
    float ss = 0.f;
    #pragma unroll
    for (int u = 0; u < VPT; ++u) {
        float v = acc[u] * dn + bias[c0 + u];
        if (DO_ELU) v = v > 0.f ? v : expm1f(v);
        val[u] = v;
        ss += v * v;
    }
    #pragma unroll
    for (int off = 32; off > 0; off >>= 1) ss += __shfl_xor(ss, off, 64);
    const float inv = 1.0f / fmaxf(sqrtf(ss), 1e-12f);
    #pragma unroll
    for (int u = 0; u < VPT; ++u) val[u] *= inv;
    if (VPT == 4)
        *(float4*)(out + (size_t)node * D + c0) =
            make_float4(val[0], val[1], val[2], val[3 % VPT]);
    else
        *(float2*)(out + (size_t)node * D + c0) = make_float2(val[0], val[1 % VPT]);
}

// ---------------------------------------------------------------------------
extern "C" void kernel_launch(void* const* d_in, const int* in_sizes, int n_in,
                              void* d_out, int out_size, void* d_ws, size_t ws_size,
                              hipStream_t stream) {
    const float* x  = (const float*)d_in[0];
    const float* A  = (const float*)d_in[1];
    const float* W1 = (const float*)d_in[2];
    const float* b1 = (const float*)d_in[3];
    const float* W2 = (const float*)d_in[4];
    const float* b2 = (const float*)d_in[5];

    float* out = (float*)d_out;
    float* z2  = out;                                   // 16384 x 128
    float* z1  = out + (size_t)N_NODES * OUT_DIM;       // 16384 x 256

    char* p = (char*)d_ws;
    int*   adj = (int*)p;            p += (size_t)N_NODES * MAXDEG * sizeof(int);
    int*   cnt = (int*)p;            p += (size_t)N_NODES * sizeof(int);
    float* din = (float*)p;          p += (size_t)N_NODES * sizeof(float);
    unsigned short* h1 = (unsigned short*)p;
    p += (size_t)N_NODES * HID_DIM * sizeof(unsigned short);
    unsigned short* h2 = (unsigned short*)p;

    // 1) [A-scan || h1 = bf16(x @ W1)] fused
    scan_gemm_kernel<<<5120, 256, 0, stream>>>(A, adj, cnt, din, x, W1, h1);

    // 2) z1 = l2norm(elu(agg(h1*din) * din + b1))   (f32 out)
    agg_kernel<HID_DIM, 4, true><<<N_NODES / 4, 256, 0, stream>>>(
        h1, adj, cnt, din, b1, z1);

    // 3) h2 = bf16(z1 @ W2)
    gemm_kernel<<<dim3(OUT_DIM / 64, N_NODES / 64), 256, 0, stream>>>(
        z1, W2, h2, HID_DIM, OUT_DIM);

    // 4) z2 = l2norm(agg(h2*din) * din + b2)        (f32 out)
    agg_kernel<OUT_DIM, 2, false><<<N_NODES / 4, 256, 0, stream>>>(
        h2, adj, cnt, din, b2, z2);
}